// Round 8
// baseline (739.368 us; speedup 1.0000x reference)
//
#include <hip/hip_runtime.h>
#include <math.h>

#define NN 40000
#define EE 400000
#define BB 256

typedef __attribute__((ext_vector_type(8))) short short8;
typedef __attribute__((ext_vector_type(4))) float f32x4;
typedef __attribute__((address_space(1))) unsigned int glb_u32;
typedef __attribute__((address_space(3))) unsigned int lds_u32;

#define MFMA16 __builtin_amdgcn_mfma_f32_16x16x32_bf16

__device__ __forceinline__ float sigf(float x) { return 1.0f / (1.0f + __expf(-x)); }
__device__ __forceinline__ float tanhfast(float x) { return 2.0f / (1.0f + __expf(-2.0f * x)) - 1.0f; }
__device__ __forceinline__ unsigned short f2b(float f) {
    unsigned u = __float_as_uint(f);
    u += 0x7FFFu + ((u >> 16) & 1u);
    return (unsigned short)(u >> 16);
}
__device__ __forceinline__ float b2f(unsigned short h) { return __uint_as_float(((unsigned)h) << 16); }
__device__ __forceinline__ short8 ld8(const unsigned short* p) {
    return __builtin_bit_cast(short8, *(const uint4*)p);
}
__device__ __forceinline__ void gld_lds16(const void* g, void* l) {
    __builtin_amdgcn_global_load_lds((const glb_u32*)g, (lds_u32*)l, 16, 0, 0);
}

// ---------------- fp32 -> bf16 conversion ----------------
__global__ void k_f2b(const float* __restrict__ s, unsigned short* __restrict__ d, int n4) {
    int i = blockIdx.x * blockDim.x + threadIdx.x;
    if (i < n4) {
        float4 v = ((const float4*)s)[i];
        ushort4 o;
        o.x = f2b(v.x); o.y = f2b(v.y); o.z = f2b(v.z); o.w = f2b(v.w);
        ((ushort4*)d)[i] = o;
    }
}

// ---------------- Wfused = Wih @ W  [768x256] bf16, vib = Wih @ b [768] ----------------
__global__ __launch_bounds__(256) void k_wfuse(const float* __restrict__ Wih,
                                               const float* __restrict__ W,
                                               const float* __restrict__ b,
                                               unsigned short* __restrict__ Wf,
                                               float* __restrict__ vib) {
    int g = blockIdx.x;   // 768
    int c = threadIdx.x;  // 256
    __shared__ float row[256];
    __shared__ float red[256];
    row[c] = Wih[(size_t)g * 256 + c];
    __syncthreads();
    float acc = 0.f;
#pragma unroll 8
    for (int o = 0; o < 256; o++) acc += row[o] * W[(size_t)o * 256 + c];
    Wf[(size_t)g * 256 + c] = f2b(acc);
    red[c] = row[c] * b[c];
    __syncthreads();
    for (int off = 128; off; off >>= 1) {
        if (c < off) red[c] += red[c + off];
        __syncthreads();
    }
    if (c == 0) vib[g] = red[0];
}

// ---------------- weight prepack into per-(bn_tile, K-step) fragment order ----------------
// unit id = (((bn_t*8 + ks)*6 + q)*4 + t)*64 + lane ; each unit = 16 B (8 bf16)
// element: col = bn_t*64 + t*16 + (lane&15); k = ks*32 + (lane>>4)*8 .. +8
__global__ void k_wpack(const unsigned short* __restrict__ Wf,
                        const float* __restrict__ Whh,
                        unsigned short* __restrict__ Wp) {
    int id = blockIdx.x * 256 + threadIdx.x;  // 49152 units
    if (id >= 49152) return;
    int lane = id & 63;
    int t = (id >> 6) & 3;
    int q = (id >> 8) % 6;
    int bk = (id >> 8) / 6;
    int ks = bk & 7, bn_t = bk >> 3;
    int col = bn_t * 64 + t * 16 + (lane & 15);
    int k = ks * 32 + (lane >> 4) * 8;
    unsigned short o[8];
    if (q < 3) {
        const unsigned short* s = Wf + (size_t)(q * 256 + col) * 256 + k;
#pragma unroll
        for (int j = 0; j < 8; j++) o[j] = s[j];
    } else {
        const float* s = Whh + (size_t)((q - 3) * 256 + col) * 256 + k;
#pragma unroll
        for (int j = 0; j < 8; j++) o[j] = f2b(s[j]);
    }
    *(uint4*)(Wp + (size_t)id * 8) = *(const uint4*)o;
}

// ---------------- CSR build ----------------
__global__ void k_zeroi(int* __restrict__ p, int n) {
    int i = blockIdx.x * blockDim.x + threadIdx.x;
    if (i < n) p[i] = 0;
}

__global__ void k_hist(const int* __restrict__ dst, int* __restrict__ cnt) {
    int e = blockIdx.x * blockDim.x + threadIdx.x;
    if (e < EE) atomicAdd(&cnt[dst[e]], 1);
}

__global__ __launch_bounds__(1024) void k_scanA(const int* __restrict__ cnt, int* __restrict__ rp,
                                                int* __restrict__ bsum) {
    __shared__ int sm[1024];
    int b = blockIdx.x, t = threadIdx.x;
    int i = b * 1024 + t;
    sm[t] = (i < NN) ? cnt[i] : 0;
    __syncthreads();
    for (int off = 1; off < 1024; off <<= 1) {
        int u = (t >= off) ? sm[t - off] : 0;
        __syncthreads();
        sm[t] += u;
        __syncthreads();
    }
    if (i < NN) rp[i + 1] = sm[t];
    if (t == 1023) bsum[b] = sm[1023];
}

__global__ void k_scanB(const int* __restrict__ bsum, int* __restrict__ boff, int* __restrict__ rp) {
    if (threadIdx.x == 0) {
        int run = 0;
        for (int k = 0; k < 40; k++) { boff[k] = run; run += bsum[k]; }
        rp[0] = 0;
    }
}

__global__ void k_scanC(int* __restrict__ rp, const int* __restrict__ boff) {
    int i = blockIdx.x * 256 + threadIdx.x;
    if (i < NN) rp[i + 1] += boff[i >> 10];
}

__global__ void k_fill(const int* __restrict__ src, const int* __restrict__ dst,
                       const int* __restrict__ rp, int* __restrict__ cur, int* __restrict__ cs) {
    int e = blockIdx.x * blockDim.x + threadIdx.x;
    if (e < EE) {
        int v = dst[e];
        int pos = rp[v] + atomicAdd(&cur[v], 1);
        cs[pos] = src[e];
    }
}

// ---------------- message aggregation: 2 nodes/wave, 16 B/lane, 8-deep ----------------
__device__ __forceinline__ void acc8(float* a, uint4 v) {
    a[0] += b2f((unsigned short)(v.x & 0xFFFF));
    a[1] += b2f((unsigned short)(v.x >> 16));
    a[2] += b2f((unsigned short)(v.y & 0xFFFF));
    a[3] += b2f((unsigned short)(v.y >> 16));
    a[4] += b2f((unsigned short)(v.z & 0xFFFF));
    a[5] += b2f((unsigned short)(v.z >> 16));
    a[6] += b2f((unsigned short)(v.w & 0xFFFF));
    a[7] += b2f((unsigned short)(v.w >> 16));
}

__global__ __launch_bounds__(256) void k_aggr(const unsigned short* __restrict__ Hb,
                                              const int* __restrict__ rp,
                                              const int* __restrict__ cs,
                                              unsigned short* __restrict__ Agg) {
    int v = blockIdx.x * 8 + (threadIdx.x >> 5);
    int hl = threadIdx.x & 31;
    int s = rp[v], e = rp[v + 1];
    float a[8] = {};
    int j = s;
    for (; j + 8 <= e; j += 8) {
        uint4 x0 = *(const uint4*)&Hb[(size_t)cs[j] * 256 + hl * 8];
        uint4 x1 = *(const uint4*)&Hb[(size_t)cs[j + 1] * 256 + hl * 8];
        uint4 x2 = *(const uint4*)&Hb[(size_t)cs[j + 2] * 256 + hl * 8];
        uint4 x3 = *(const uint4*)&Hb[(size_t)cs[j + 3] * 256 + hl * 8];
        uint4 x4 = *(const uint4*)&Hb[(size_t)cs[j + 4] * 256 + hl * 8];
        uint4 x5 = *(const uint4*)&Hb[(size_t)cs[j + 5] * 256 + hl * 8];
        uint4 x6 = *(const uint4*)&Hb[(size_t)cs[j + 6] * 256 + hl * 8];
        uint4 x7 = *(const uint4*)&Hb[(size_t)cs[j + 7] * 256 + hl * 8];
        acc8(a, x0); acc8(a, x1); acc8(a, x2); acc8(a, x3);
        acc8(a, x4); acc8(a, x5); acc8(a, x6); acc8(a, x7);
    }
    for (; j < e; j++) {
        uint4 x = *(const uint4*)&Hb[(size_t)cs[j] * 256 + hl * 8];
        acc8(a, x);
    }
    uint4 o;
    o.x = (unsigned)f2b(a[0]) | ((unsigned)f2b(a[1]) << 16);
    o.y = (unsigned)f2b(a[2]) | ((unsigned)f2b(a[3]) << 16);
    o.z = (unsigned)f2b(a[4]) | ((unsigned)f2b(a[5]) << 16);
    o.w = (unsigned)f2b(a[6]) | ((unsigned)f2b(a[7]) << 16);
    *(uint4*)&Agg[(size_t)v * 256 + hl * 8] = o;
}

// ---------------- fused GRU (R19): R11 minus the A-prefetch dbuf => 3 waves/SIMD ------
// Single delta vs R18 (the banked 78us/722us baseline): drop nm0..nh1 (16 VGPRs).
// Rationale: 84 arch + 96 acc = 180 regs > 170 (512-reg SIMD file / 3) kept us at 2
// waves/SIMD while LDS allowed 3 blocks/CU. The A rows are re-read every round (same
// 16 rows, next 64B slice) so rounds 1-7 A-loads are L1-hits — the prefetch hid latency
// that mostly isn't there. ~164 regs -> 3 waves/SIMD, 3 blocks/CU, +50% TLP to cover
// the per-round stage drain. Round = {vmcnt(0), barrier, A-loads, STAGE(ks+1), MFMA};
// A issued BEFORE the 6 stage DMAs so the compiler's A-wait is vmcnt(6) (stage stays
// in flight). Tripwires: VGPR>=78 (didn't fit), WRITE>25MB (spill).
__global__ __launch_bounds__(256, 3) void k_gru(const unsigned short* __restrict__ Mb,
                                                const unsigned short* __restrict__ Hb,
                                                const char* __restrict__ Wp,
                                                const float* __restrict__ bih,
                                                const float* __restrict__ bhh,
                                                const float* __restrict__ vib,
                                                const int* __restrict__ cnt,
                                                unsigned short* __restrict__ Hout, int fin) {
    __shared__ uint4 Wl[2][1536];  // 2 x 24 KB
    const int tid = threadIdx.x;
    const int lane = tid & 63, wid = tid >> 6;
    const int wr = wid >> 1, wc = wid & 1;
    // bijective XCD-chunk swizzle: 2500 = 8*312 + 4
    const int p = blockIdx.x;
    const int xcd = p & 7, rank = p >> 3;
    const int logical = (xcd < 4 ? xcd * 313 : 1252 + (xcd - 4) * 312) + rank;
    const int bm = (logical >> 2) * 64, bn_t = logical & 3, bn = bn_t * 64;
    const int l15 = lane & 15, lk = lane >> 4;

    const unsigned short* m0p = Mb + (size_t)(bm + wr * 32 + l15) * 256 + lk * 8;
    const unsigned short* m1p = m0p + 16 * 256;
    const unsigned short* h0p = Hb + (size_t)(bm + wr * 32 + l15) * 256 + lk * 8;
    const unsigned short* h1p = h0p + 16 * 256;

    const char* wbase = Wp + (size_t)bn_t * 8 * 24576;
    char* lds0 = (char*)&Wl[0][0];
    char* lds1 = (char*)&Wl[1][0];
    const int soff = wid * 1024 + lane * 16;

#define STAGE(b, ks)                                                        \
    {                                                                       \
        const char* gs = wbase + (ks) * 24576;                              \
        char* lb = (b) ? lds1 : lds0;                                       \
        _Pragma("unroll") for (int i = 0; i < 6; i++)                       \
            gld_lds16(gs + i * 4096 + soff, lb + i * 4096 + wid * 1024);    \
    }

    f32x4 acc[6][2][2] = {};
    short8 m0, m1, h0, h1;

    STAGE(0, 0);

    for (int ks = 0; ks < 8; ks++) {
        int cur = ks & 1;
        // only the current stage's 6 DMAs are in flight at round top
        asm volatile("s_waitcnt vmcnt(0)" ::: "memory");
        __builtin_amdgcn_s_barrier();
        __builtin_amdgcn_sched_barrier(0);
        {
            const int ke = ks * 32;  // byte offset ks*64 folds into the load offset
            m0 = ld8(m0p + ke); m1 = ld8(m1p + ke);
            h0 = ld8(h0p + ke); h1 = ld8(h1p + ke);
        }
        asm volatile("" ::: "memory");  // pin A-loads BEFORE the stage DMAs
        if (ks < 7) STAGE(cur ^ 1, ks + 1);
        __builtin_amdgcn_s_setprio(1);
#pragma unroll
        for (int q = 0; q < 6; q++) {
            short8 b0 = __builtin_bit_cast(short8, Wl[cur][(q * 4 + wc * 2 + 0) * 64 + lane]);
            short8 b1 = __builtin_bit_cast(short8, Wl[cur][(q * 4 + wc * 2 + 1) * 64 + lane]);
            short8 a0 = q < 3 ? m0 : h0;
            short8 a1 = q < 3 ? m1 : h1;
            acc[q][0][0] = MFMA16(a0, b0, acc[q][0][0], 0, 0, 0);
            acc[q][1][0] = MFMA16(a1, b0, acc[q][1][0], 0, 0, 0);
            acc[q][0][1] = MFMA16(a0, b1, acc[q][0][1], 0, 0, 0);
            acc[q][1][1] = MFMA16(a1, b1, acc[q][1][1], 0, 0, 0);
        }
        __builtin_amdgcn_s_setprio(0);
    }
#undef STAGE

    const int lk4 = lk * 4;
#pragma unroll
    for (int f = 0; f < 2; f++)
#pragma unroll
        for (int t = 0; t < 2; t++) {
            int col = bn + wc * 32 + t * 16 + l15;
            float bi0 = bih[col], bi1 = bih[col + 256], bi2 = bih[col + 512];
            float bh0 = bhh[col], bh1 = bhh[col + 256], bh2 = bhh[col + 512];
            float v0 = vib[col], v1 = vib[col + 256], v2 = vib[col + 512];
#pragma unroll
            for (int r = 0; r < 4; r++) {
                int n = bm + wr * 32 + f * 16 + lk4 + r;
                float cf = (float)cnt[n];
                float ho = b2f(Hb[(size_t)n * 256 + col]);
                float irv = acc[0][f][t][r] + bi0 + cf * v0;
                float izv = acc[1][f][t][r] + bi1 + cf * v1;
                float inv = acc[2][f][t][r] + bi2 + cf * v2;
                float hrv = acc[3][f][t][r] + bh0;
                float hzv = acc[4][f][t][r] + bh1;
                float hnv = acc[5][f][t][r] + bh2;
                float rg = sigf(irv + hrv);
                float zg = sigf(izv + hzv);
                float nv = tanhfast(inv + rg * hnv);
                float v = (1.0f - zg) * nv + zg * ho;
                if (fin) v = sigf(v);
                Hout[(size_t)n * 256 + col] = f2b(v);
            }
        }
}

// ---------------- attention pooling ----------------
__global__ __launch_bounds__(256) void k_gate(const unsigned short* __restrict__ H,
                                              const float* __restrict__ Wg,
                                              const float* __restrict__ bg,
                                              float* __restrict__ gate) {
    int v = blockIdx.x * 4 + (threadIdx.x >> 6);
    int lane = threadIdx.x & 63;
    if (v >= NN) return;
    ushort4 hv = *(const ushort4*)&H[(size_t)v * 256 + lane * 4];
    float4 wv = *(const float4*)&Wg[lane * 4];
    float s = b2f(hv.x) * wv.x + b2f(hv.y) * wv.y + b2f(hv.z) * wv.z + b2f(hv.w) * wv.w;
    for (int off = 32; off; off >>= 1) s += __shfl_down(s, off);
    if (lane == 0) gate[v] = s + bg[0];
}

__global__ void k_bounds(const int* __restrict__ ids, int* __restrict__ gs, int* __restrict__ ge) {
    int b = threadIdx.x;
    int lo = 0, hi = NN;
    while (lo < hi) { int mid = (lo + hi) >> 1; if (ids[mid] < b) lo = mid + 1; else hi = mid; }
    gs[b] = lo;
    lo = 0; hi = NN;
    int key = b + 1;
    while (lo < hi) { int mid = (lo + hi) >> 1; if (ids[mid] < key) lo = mid + 1; else hi = mid; }
    ge[b] = lo;
}

__global__ __launch_bounds__(256) void k_pool(const unsigned short* __restrict__ H,
                                              const float* __restrict__ gate,
                                              const int* __restrict__ gs,
                                              const int* __restrict__ ge,
                                              float* __restrict__ pooled) {
    int b = blockIdx.x;
    int s = gs[b], e = ge[b];
    int t = threadIdx.x;
    __shared__ float red[256];
    __shared__ float wsh[256];
    float mx = -INFINITY;
    for (int n = s + t; n < e; n += 256) mx = fmaxf(mx, gate[n]);
    red[t] = mx;
    __syncthreads();
    for (int off = 128; off; off >>= 1) {
        if (t < off) red[t] = fmaxf(red[t], red[t + off]);
        __syncthreads();
    }
    mx = red[0];
    __syncthreads();
    float sm = 0.f;
    for (int n = s + t; n < e; n += 256) sm += __expf(gate[n] - mx);
    red[t] = sm;
    __syncthreads();
    for (int off = 128; off; off >>= 1) {
        if (t < off) red[t] += red[t + off];
        __syncthreads();
    }
    float denom = red[0];
    __syncthreads();
    float acc = 0.f;
    for (int c = s; c < e; c += 256) {
        int n = c + t;
        wsh[t] = (n < e) ? __expf(gate[n] - mx) / denom : 0.f;
        __syncthreads();
        int lim = e - c; if (lim > 256) lim = 256;
        for (int q = 0; q < lim; q++) acc += wsh[q] * b2f(H[(size_t)(c + q) * 256 + t]);
        __syncthreads();
    }
    pooled[(size_t)b * 256 + t] = acc;
}

__global__ void k_out(const float* __restrict__ pooled, const float* __restrict__ Wo,
                      const float* __restrict__ bo, float* __restrict__ out) {
    int b = blockIdx.x;
    int lane = threadIdx.x;  // 64
    float4 pv = *(const float4*)&pooled[(size_t)b * 256 + lane * 4];
    float4 wv = *(const float4*)&Wo[lane * 4];
    float s = pv.x * wv.x + pv.y * wv.y + pv.z * wv.z + pv.w * wv.w;
    for (int off = 32; off; off >>= 1) s += __shfl_down(s, off);
    if (lane == 0) out[b] = sigf(s + bo[0]);
}

// ---------------- launch ----------------
extern "C" void kernel_launch(void* const* d_in, const int* in_sizes, int n_in,
                              void* d_out, int out_size, void* d_ws, size_t ws_size,
                              hipStream_t stream) {
    const float* features = (const float*)d_in[0];
    const int* src = (const int*)d_in[1];
    const int* dst = (const int*)d_in[2];
    const int* gids = (const int*)d_in[3];
    const float* W[2]   = {(const float*)d_in[4],  (const float*)d_in[10]};
    const float* bW[2]  = {(const float*)d_in[5],  (const float*)d_in[11]};
    const float* Wih[2] = {(const float*)d_in[6],  (const float*)d_in[12]};
    const float* Whh[2] = {(const float*)d_in[7],  (const float*)d_in[13]};
    const float* bih[2] = {(const float*)d_in[8],  (const float*)d_in[14]};
    const float* bhh[2] = {(const float*)d_in[9],  (const float*)d_in[15]};
    const float* Wg = (const float*)d_in[16];
    const float* bg = (const float*)d_in[17];
    const float* Wo = (const float*)d_in[18];
    const float* bo = (const float*)d_in[19];
    float* out = (float*)d_out;

    char* p = (char*)d_ws;
    auto alloc = [&](size_t bytes) {
        char* r = p;
        p += (bytes + 255) / 256 * 256;
        return r;
    };
    unsigned short* hbF = (unsigned short*)alloc((size_t)NN * 256 * 2);
    unsigned short* hA = (unsigned short*)alloc((size_t)NN * 256 * 2);
    unsigned short* hB = (unsigned short*)alloc((size_t)NN * 256 * 2);
    unsigned short* agg = (unsigned short*)alloc((size_t)NN * 256 * 2);
    unsigned short* Wfb[2], *Wpk[2];
    float* vib[2];
    for (int i = 0; i < 2; i++) {
        Wfb[i] = (unsigned short*)alloc((size_t)768 * 256 * 2);
        Wpk[i] = (unsigned short*)alloc((size_t)49152 * 16);
        vib[i] = (float*)alloc((size_t)768 * 4);
    }
    int* rp = (int*)alloc((size_t)(NN + 1) * 4);
    int* cnt = (int*)alloc((size_t)NN * 4);
    int* cur = (int*)alloc((size_t)NN * 4);
    int* cs = (int*)alloc((size_t)EE * 4);
    int* bsum = (int*)alloc(64 * 4);
    int* boff = (int*)alloc(64 * 4);
    float* gate = (float*)alloc((size_t)NN * 4);
    int* gsb = (int*)alloc((size_t)BB * 4);
    int* geb = (int*)alloc((size_t)BB * 4);
    float* pooled = (float*)alloc((size_t)BB * 256 * 4);

    // conversions + fused/packed weights
    k_f2b<<<(NN * 256 / 4 + 255) / 256, 256, 0, stream>>>(features, hbF, NN * 256 / 4);
    for (int i = 0; i < 2; i++) {
        k_wfuse<<<768, 256, 0, stream>>>(Wih[i], W[i], bW[i], Wfb[i], vib[i]);
        k_wpack<<<192, 256, 0, stream>>>(Wfb[i], Whh[i], Wpk[i]);
    }

    // CSR build (by dst), parallel scan
    k_zeroi<<<(NN + 255) / 256, 256, 0, stream>>>(cnt, NN);
    k_zeroi<<<(NN + 255) / 256, 256, 0, stream>>>(cur, NN);
    k_hist<<<(EE + 255) / 256, 256, 0, stream>>>(dst, cnt);
    k_scanA<<<40, 1024, 0, stream>>>(cnt, rp, bsum);
    k_scanB<<<1, 64, 0, stream>>>(bsum, boff, rp);
    k_scanC<<<157, 256, 0, stream>>>(rp, boff);
    k_fill<<<(EE + 255) / 256, 256, 0, stream>>>(src, dst, rp, cur, cs);
    k_bounds<<<1, 256, 0, stream>>>(gids, gsb, geb);

    const unsigned short* hcur = hbF;
    unsigned short* hnext = hA;
    for (int li = 0; li < 2; li++) {
        for (int s = 0; s < 3; s++) {
            k_aggr<<<5000, 256, 0, stream>>>(hcur, rp, cs, agg);
            int fin = (s == 2) ? 1 : 0;
            k_gru<<<2500, 256, 0, stream>>>(agg, hcur, (const char*)Wpk[li], bih[li], bhh[li],
                                            vib[li], cnt, hnext, fin);
            hcur = hnext;
            hnext = (hnext == hA) ? hB : hA;
        }
    }
    k_gate<<<10000, 256, 0, stream>>>(hcur, Wg, bg, gate);
    k_pool<<<BB, 256, 0, stream>>>(hcur, gate, gsb, geb, pooled);
    k_out<<<BB, 64, 0, stream>>>(pooled, Wo, bo, out);
}

// Round 9
// 703.314 us; speedup vs baseline: 1.0513x; 1.0513x over previous
//
#include <hip/hip_runtime.h>
#include <math.h>

#define NN 40000
#define EE 400000
#define BB 256

typedef __attribute__((ext_vector_type(8))) short short8;
typedef __attribute__((ext_vector_type(4))) float f32x4;
typedef __attribute__((address_space(1))) unsigned int glb_u32;
typedef __attribute__((address_space(3))) unsigned int lds_u32;

#define MFMA16 __builtin_amdgcn_mfma_f32_16x16x32_bf16

__device__ __forceinline__ float sigf(float x) { return 1.0f / (1.0f + __expf(-x)); }
__device__ __forceinline__ float tanhfast(float x) { return 2.0f / (1.0f + __expf(-2.0f * x)) - 1.0f; }
__device__ __forceinline__ unsigned short f2b(float f) {
    unsigned u = __float_as_uint(f);
    u += 0x7FFFu + ((u >> 16) & 1u);
    return (unsigned short)(u >> 16);
}
__device__ __forceinline__ float b2f(unsigned short h) { return __uint_as_float(((unsigned)h) << 16); }
__device__ __forceinline__ short8 ld8(const unsigned short* p) {
    return __builtin_bit_cast(short8, *(const uint4*)p);
}
__device__ __forceinline__ void gld_lds16(const void* g, void* l) {
    __builtin_amdgcn_global_load_lds((const glb_u32*)g, (lds_u32*)l, 16, 0, 0);
}

// ---------------- fp32 -> bf16 conversion ----------------
__global__ void k_f2b(const float* __restrict__ s, unsigned short* __restrict__ d, int n4) {
    int i = blockIdx.x * blockDim.x + threadIdx.x;
    if (i < n4) {
        float4 v = ((const float4*)s)[i];
        ushort4 o;
        o.x = f2b(v.x); o.y = f2b(v.y); o.z = f2b(v.z); o.w = f2b(v.w);
        ((ushort4*)d)[i] = o;
    }
}

// ---------------- Wfused = Wih @ W  [768x256] bf16, vib = Wih @ b [768] ----------------
__global__ __launch_bounds__(256) void k_wfuse(const float* __restrict__ Wih,
                                               const float* __restrict__ W,
                                               const float* __restrict__ b,
                                               unsigned short* __restrict__ Wf,
                                               float* __restrict__ vib) {
    int g = blockIdx.x;   // 768
    int c = threadIdx.x;  // 256
    __shared__ float row[256];
    __shared__ float red[256];
    row[c] = Wih[(size_t)g * 256 + c];
    __syncthreads();
    float acc = 0.f;
#pragma unroll 8
    for (int o = 0; o < 256; o++) acc += row[o] * W[(size_t)o * 256 + c];
    Wf[(size_t)g * 256 + c] = f2b(acc);
    red[c] = row[c] * b[c];
    __syncthreads();
    for (int off = 128; off; off >>= 1) {
        if (c < off) red[c] += red[c + off];
        __syncthreads();
    }
    if (c == 0) vib[g] = red[0];
}

// ---------------- weight prepack into per-(bn_tile, K-step) fragment order ----------------
// unit id = (((bn_t*8 + ks)*6 + q)*4 + t)*64 + lane ; each unit = 16 B (8 bf16)
// element: col = bn_t*64 + t*16 + (lane&15); k = ks*32 + (lane>>4)*8 .. +8
__global__ void k_wpack(const unsigned short* __restrict__ Wf,
                        const float* __restrict__ Whh,
                        unsigned short* __restrict__ Wp) {
    int id = blockIdx.x * 256 + threadIdx.x;  // 49152 units
    if (id >= 49152) return;
    int lane = id & 63;
    int t = (id >> 6) & 3;
    int q = (id >> 8) % 6;
    int bk = (id >> 8) / 6;
    int ks = bk & 7, bn_t = bk >> 3;
    int col = bn_t * 64 + t * 16 + (lane & 15);
    int k = ks * 32 + (lane >> 4) * 8;
    unsigned short o[8];
    if (q < 3) {
        const unsigned short* s = Wf + (size_t)(q * 256 + col) * 256 + k;
#pragma unroll
        for (int j = 0; j < 8; j++) o[j] = s[j];
    } else {
        const float* s = Whh + (size_t)((q - 3) * 256 + col) * 256 + k;
#pragma unroll
        for (int j = 0; j < 8; j++) o[j] = f2b(s[j]);
    }
    *(uint4*)(Wp + (size_t)id * 8) = *(const uint4*)o;
}

// ---------------- CSR build ----------------
__global__ void k_zeroi(int* __restrict__ p, int n) {
    int i = blockIdx.x * blockDim.x + threadIdx.x;
    if (i < n) p[i] = 0;
}

__global__ void k_hist(const int* __restrict__ dst, int* __restrict__ cnt) {
    int e = blockIdx.x * blockDim.x + threadIdx.x;
    if (e < EE) atomicAdd(&cnt[dst[e]], 1);
}

__global__ __launch_bounds__(1024) void k_scanA(const int* __restrict__ cnt, int* __restrict__ rp,
                                                int* __restrict__ bsum) {
    __shared__ int sm[1024];
    int b = blockIdx.x, t = threadIdx.x;
    int i = b * 1024 + t;
    sm[t] = (i < NN) ? cnt[i] : 0;
    __syncthreads();
    for (int off = 1; off < 1024; off <<= 1) {
        int u = (t >= off) ? sm[t - off] : 0;
        __syncthreads();
        sm[t] += u;
        __syncthreads();
    }
    if (i < NN) rp[i + 1] = sm[t];
    if (t == 1023) bsum[b] = sm[1023];
}

__global__ void k_scanB(const int* __restrict__ bsum, int* __restrict__ boff, int* __restrict__ rp) {
    if (threadIdx.x == 0) {
        int run = 0;
        for (int k = 0; k < 40; k++) { boff[k] = run; run += bsum[k]; }
        rp[0] = 0;
    }
}

__global__ void k_scanC(int* __restrict__ rp, const int* __restrict__ boff) {
    int i = blockIdx.x * 256 + threadIdx.x;
    if (i < NN) rp[i + 1] += boff[i >> 10];
}

__global__ void k_fill(const int* __restrict__ src, const int* __restrict__ dst,
                       const int* __restrict__ rp, int* __restrict__ cur, int* __restrict__ cs) {
    int e = blockIdx.x * blockDim.x + threadIdx.x;
    if (e < EE) {
        int v = dst[e];
        int pos = rp[v] + atomicAdd(&cur[v], 1);
        cs[pos] = src[e];
    }
}

// ---------------- message aggregation (R20): FULL wave per node ----------------------
// Old: 2 nodes/wave (32 lanes each) -> every iteration runs max(deg_a, deg_b) with
// exec-masking (~20% wasted for Poisson(10)), half-width load chains. New: all 64 lanes
// on one node; halves process even/odd edges (2 edges/iter, 8-edge unrolled batch);
// one cross-half __shfl_xor reduction (8 shuffles) at the end; lanes 0-31 write.
// Same total bytes gathered; uniform trip count; 2x fewer iterations per node.
__device__ __forceinline__ void acc8(float* a, uint4 v) {
    a[0] += b2f((unsigned short)(v.x & 0xFFFF));
    a[1] += b2f((unsigned short)(v.x >> 16));
    a[2] += b2f((unsigned short)(v.y & 0xFFFF));
    a[3] += b2f((unsigned short)(v.y >> 16));
    a[4] += b2f((unsigned short)(v.z & 0xFFFF));
    a[5] += b2f((unsigned short)(v.z >> 16));
    a[6] += b2f((unsigned short)(v.w & 0xFFFF));
    a[7] += b2f((unsigned short)(v.w >> 16));
}

__global__ __launch_bounds__(256) void k_aggr(const unsigned short* __restrict__ Hb,
                                              const int* __restrict__ rp,
                                              const int* __restrict__ cs,
                                              unsigned short* __restrict__ Agg) {
    int v = blockIdx.x * 4 + (threadIdx.x >> 6);
    int lane = threadIdx.x & 63;
    int hl = lane & 31, half = lane >> 5;
    int s = rp[v], e = rp[v + 1];
    float a[8] = {};
    int j = s;
    for (; j + 8 <= e; j += 8) {  // 8 edges: 4 independent loads/lane
        uint4 x0 = *(const uint4*)&Hb[(size_t)cs[j + half] * 256 + hl * 8];
        uint4 x1 = *(const uint4*)&Hb[(size_t)cs[j + 2 + half] * 256 + hl * 8];
        uint4 x2 = *(const uint4*)&Hb[(size_t)cs[j + 4 + half] * 256 + hl * 8];
        uint4 x3 = *(const uint4*)&Hb[(size_t)cs[j + 6 + half] * 256 + hl * 8];
        acc8(a, x0); acc8(a, x1); acc8(a, x2); acc8(a, x3);
    }
    for (; j + 2 <= e; j += 2) {  // pairwise tail
        uint4 x = *(const uint4*)&Hb[(size_t)cs[j + half] * 256 + hl * 8];
        acc8(a, x);
    }
    if (j < e && half == 0) {     // odd final edge
        uint4 x = *(const uint4*)&Hb[(size_t)cs[j] * 256 + hl * 8];
        acc8(a, x);
    }
#pragma unroll
    for (int i = 0; i < 8; i++) a[i] += __shfl_xor(a[i], 32);
    if (half == 0) {
        uint4 o;
        o.x = (unsigned)f2b(a[0]) | ((unsigned)f2b(a[1]) << 16);
        o.y = (unsigned)f2b(a[2]) | ((unsigned)f2b(a[3]) << 16);
        o.z = (unsigned)f2b(a[4]) | ((unsigned)f2b(a[5]) << 16);
        o.w = (unsigned)f2b(a[6]) | ((unsigned)f2b(a[7]) << 16);
        *(uint4*)&Agg[(size_t)v * 256 + hl * 8] = o;
    }
}

// ---------------- fused GRU: dbuf LDS weights, counted vmcnt, XCD swizzle (R11) + T5 ----
// VERBATIM R18 (banked 78us/dispatch, 720us total). Do not touch: R12-R17 and R19
// bracketed this point from every axis (pipeline depth, tile size, LDS residency,
// occupancy, barrier removal, register diet) and all regressed. Register count and
// occupancy are not steerable from source at this structure (R19: dropping the
// A-prefetch left VGPR_Count at 84 and added +3.5us from the serialized drain).
__global__ __launch_bounds__(256, 3) void k_gru(const unsigned short* __restrict__ Mb,
                                                const unsigned short* __restrict__ Hb,
                                                const char* __restrict__ Wp,
                                                const float* __restrict__ bih,
                                                const float* __restrict__ bhh,
                                                const float* __restrict__ vib,
                                                const int* __restrict__ cnt,
                                                unsigned short* __restrict__ Hout, int fin) {
    __shared__ uint4 Wl[2][1536];  // 2 x 24 KB
    const int tid = threadIdx.x;
    const int lane = tid & 63, wid = tid >> 6;
    const int wr = wid >> 1, wc = wid & 1;
    // bijective XCD-chunk swizzle: 2500 = 8*312 + 4
    const int p = blockIdx.x;
    const int xcd = p & 7, rank = p >> 3;
    const int logical = (xcd < 4 ? xcd * 313 : 1252 + (xcd - 4) * 312) + rank;
    const int bm = (logical >> 2) * 64, bn_t = logical & 3, bn = bn_t * 64;
    const int l15 = lane & 15, lk = lane >> 4;

    const unsigned short* m0p = Mb + (size_t)(bm + wr * 32 + l15) * 256 + lk * 8;
    const unsigned short* m1p = m0p + 16 * 256;
    const unsigned short* h0p = Hb + (size_t)(bm + wr * 32 + l15) * 256 + lk * 8;
    const unsigned short* h1p = h0p + 16 * 256;

    const char* wbase = Wp + (size_t)bn_t * 8 * 24576;
    char* lds0 = (char*)&Wl[0][0];
    char* lds1 = (char*)&Wl[1][0];
    const int soff = wid * 1024 + lane * 16;

#define STAGE(b, ks)                                                        \
    {                                                                       \
        const char* gs = wbase + (ks) * 24576;                              \
        char* lb = (b) ? lds1 : lds0;                                       \
        _Pragma("unroll") for (int i = 0; i < 6; i++)                       \
            gld_lds16(gs + i * 4096 + soff, lb + i * 4096 + wid * 1024);    \
    }

    f32x4 acc[6][2][2] = {};
    short8 m0, m1, h0, h1, nm0, nm1, nh0, nh1;

    STAGE(0, 0);
    asm volatile("" ::: "memory");  // keep A-loads AFTER the stage DMAs (vmcnt count)
    m0 = ld8(m0p); m1 = ld8(m1p); h0 = ld8(h0p); h1 = ld8(h1p);

    for (int ks = 0; ks < 8; ks++) {
        int cur = ks & 1;
        asm volatile("s_waitcnt vmcnt(4)" ::: "memory");
        __builtin_amdgcn_s_barrier();
        __builtin_amdgcn_sched_barrier(0);
        if (ks < 7) {
            STAGE(cur ^ 1, ks + 1);
            asm volatile("" ::: "memory");
            int ke = (ks + 1) * 32;
            nm0 = ld8(m0p + ke); nm1 = ld8(m1p + ke);
            nh0 = ld8(h0p + ke); nh1 = ld8(h1p + ke);
        }
        __builtin_amdgcn_s_setprio(1);
#pragma unroll
        for (int q = 0; q < 6; q++) {
            short8 b0 = __builtin_bit_cast(short8, Wl[cur][(q * 4 + wc * 2 + 0) * 64 + lane]);
            short8 b1 = __builtin_bit_cast(short8, Wl[cur][(q * 4 + wc * 2 + 1) * 64 + lane]);
            short8 a0 = q < 3 ? m0 : h0;
            short8 a1 = q < 3 ? m1 : h1;
            acc[q][0][0] = MFMA16(a0, b0, acc[q][0][0], 0, 0, 0);
            acc[q][1][0] = MFMA16(a1, b0, acc[q][1][0], 0, 0, 0);
            acc[q][0][1] = MFMA16(a0, b1, acc[q][0][1], 0, 0, 0);
            acc[q][1][1] = MFMA16(a1, b1, acc[q][1][1], 0, 0, 0);
        }
        __builtin_amdgcn_s_setprio(0);
        m0 = nm0; m1 = nm1; h0 = nh0; h1 = nh1;
    }
#undef STAGE

    const int lk4 = lk * 4;
#pragma unroll
    for (int f = 0; f < 2; f++)
#pragma unroll
        for (int t = 0; t < 2; t++) {
            int col = bn + wc * 32 + t * 16 + l15;
            float bi0 = bih[col], bi1 = bih[col + 256], bi2 = bih[col + 512];
            float bh0 = bhh[col], bh1 = bhh[col + 256], bh2 = bhh[col + 512];
            float v0 = vib[col], v1 = vib[col + 256], v2 = vib[col + 512];
#pragma unroll
            for (int r = 0; r < 4; r++) {
                int n = bm + wr * 32 + f * 16 + lk4 + r;
                float cf = (float)cnt[n];
                float ho = b2f(Hb[(size_t)n * 256 + col]);
                float irv = acc[0][f][t][r] + bi0 + cf * v0;
                float izv = acc[1][f][t][r] + bi1 + cf * v1;
                float inv = acc[2][f][t][r] + bi2 + cf * v2;
                float hrv = acc[3][f][t][r] + bh0;
                float hzv = acc[4][f][t][r] + bh1;
                float hnv = acc[5][f][t][r] + bh2;
                float rg = sigf(irv + hrv);
                float zg = sigf(izv + hzv);
                float nv = tanhfast(inv + rg * hnv);
                float v = (1.0f - zg) * nv + zg * ho;
                if (fin) v = sigf(v);
                Hout[(size_t)n * 256 + col] = f2b(v);
            }
        }
}

// ---------------- attention pooling ----------------
__global__ __launch_bounds__(256) void k_gate(const unsigned short* __restrict__ H,
                                              const float* __restrict__ Wg,
                                              const float* __restrict__ bg,
                                              float* __restrict__ gate) {
    int v = blockIdx.x * 4 + (threadIdx.x >> 6);
    int lane = threadIdx.x & 63;
    if (v >= NN) return;
    ushort4 hv = *(const ushort4*)&H[(size_t)v * 256 + lane * 4];
    float4 wv = *(const float4*)&Wg[lane * 4];
    float s = b2f(hv.x) * wv.x + b2f(hv.y) * wv.y + b2f(hv.z) * wv.z + b2f(hv.w) * wv.w;
    for (int off = 32; off; off >>= 1) s += __shfl_down(s, off);
    if (lane == 0) gate[v] = s + bg[0];
}

__global__ void k_bounds(const int* __restrict__ ids, int* __restrict__ gs, int* __restrict__ ge) {
    int b = threadIdx.x;
    int lo = 0, hi = NN;
    while (lo < hi) { int mid = (lo + hi) >> 1; if (ids[mid] < b) lo = mid + 1; else hi = mid; }
    gs[b] = lo;
    lo = 0; hi = NN;
    int key = b + 1;
    while (lo < hi) { int mid = (lo + hi) >> 1; if (ids[mid] < key) lo = mid + 1; else hi = mid; }
    ge[b] = lo;
}

__global__ __launch_bounds__(256) void k_pool(const unsigned short* __restrict__ H,
                                              const float* __restrict__ gate,
                                              const int* __restrict__ gs,
                                              const int* __restrict__ ge,
                                              float* __restrict__ pooled) {
    int b = blockIdx.x;
    int s = gs[b], e = ge[b];
    int t = threadIdx.x;
    __shared__ float red[256];
    __shared__ float wsh[256];
    float mx = -INFINITY;
    for (int n = s + t; n < e; n += 256) mx = fmaxf(mx, gate[n]);
    red[t] = mx;
    __syncthreads();
    for (int off = 128; off; off >>= 1) {
        if (t < off) red[t] = fmaxf(red[t], red[t + off]);
        __syncthreads();
    }
    mx = red[0];
    __syncthreads();
    float sm = 0.f;
    for (int n = s + t; n < e; n += 256) sm += __expf(gate[n] - mx);
    red[t] = sm;
    __syncthreads();
    for (int off = 128; off; off >>= 1) {
        if (t < off) red[t] += red[t + off];
        __syncthreads();
    }
    float denom = red[0];
    __syncthreads();
    float acc = 0.f;
    for (int c = s; c < e; c += 256) {
        int n = c + t;
        wsh[t] = (n < e) ? __expf(gate[n] - mx) / denom : 0.f;
        __syncthreads();
        int lim = e - c; if (lim > 256) lim = 256;
        for (int q = 0; q < lim; q++) acc += wsh[q] * b2f(H[(size_t)(c + q) * 256 + t]);
        __syncthreads();
    }
    pooled[(size_t)b * 256 + t] = acc;
}

__global__ void k_out(const float* __restrict__ pooled, const float* __restrict__ Wo,
                      const float* __restrict__ bo, float* __restrict__ out) {
    int b = blockIdx.x;
    int lane = threadIdx.x;  // 64
    float4 pv = *(const float4*)&pooled[(size_t)b * 256 + lane * 4];
    float4 wv = *(const float4*)&Wo[lane * 4];
    float s = pv.x * wv.x + pv.y * wv.y + pv.z * wv.z + pv.w * wv.w;
    for (int off = 32; off; off >>= 1) s += __shfl_down(s, off);
    if (lane == 0) out[b] = sigf(s + bo[0]);
}

// ---------------- launch ----------------
extern "C" void kernel_launch(void* const* d_in, const int* in_sizes, int n_in,
                              void* d_out, int out_size, void* d_ws, size_t ws_size,
                              hipStream_t stream) {
    const float* features = (const float*)d_in[0];
    const int* src = (const int*)d_in[1];
    const int* dst = (const int*)d_in[2];
    const int* gids = (const int*)d_in[3];
    const float* W[2]   = {(const float*)d_in[4],  (const float*)d_in[10]};
    const float* bW[2]  = {(const float*)d_in[5],  (const float*)d_in[11]};
    const float* Wih[2] = {(const float*)d_in[6],  (const float*)d_in[12]};
    const float* Whh[2] = {(const float*)d_in[7],  (const float*)d_in[13]};
    const float* bih[2] = {(const float*)d_in[8],  (const float*)d_in[14]};
    const float* bhh[2] = {(const float*)d_in[9],  (const float*)d_in[15]};
    const float* Wg = (const float*)d_in[16];
    const float* bg = (const float*)d_in[17];
    const float* Wo = (const float*)d_in[18];
    const float* bo = (const float*)d_in[19];
    float* out = (float*)d_out;

    char* p = (char*)d_ws;
    auto alloc = [&](size_t bytes) {
        char* r = p;
        p += (bytes + 255) / 256 * 256;
        return r;
    };
    unsigned short* hbF = (unsigned short*)alloc((size_t)NN * 256 * 2);
    unsigned short* hA = (unsigned short*)alloc((size_t)NN * 256 * 2);
    unsigned short* hB = (unsigned short*)alloc((size_t)NN * 256 * 2);
    unsigned short* agg = (unsigned short*)alloc((size_t)NN * 256 * 2);
    unsigned short* Wfb[2], *Wpk[2];
    float* vib[2];
    for (int i = 0; i < 2; i++) {
        Wfb[i] = (unsigned short*)alloc((size_t)768 * 256 * 2);
        Wpk[i] = (unsigned short*)alloc((size_t)49152 * 16);
        vib[i] = (float*)alloc((size_t)768 * 4);
    }
    int* rp = (int*)alloc((size_t)(NN + 1) * 4);
    int* cnt = (int*)alloc((size_t)NN * 4);
    int* cur = (int*)alloc((size_t)NN * 4);
    int* cs = (int*)alloc((size_t)EE * 4);
    int* bsum = (int*)alloc(64 * 4);
    int* boff = (int*)alloc(64 * 4);
    float* gate = (float*)alloc((size_t)NN * 4);
    int* gsb = (int*)alloc((size_t)BB * 4);
    int* geb = (int*)alloc((size_t)BB * 4);
    float* pooled = (float*)alloc((size_t)BB * 256 * 4);

    // conversions + fused/packed weights
    k_f2b<<<(NN * 256 / 4 + 255) / 256, 256, 0, stream>>>(features, hbF, NN * 256 / 4);
    for (int i = 0; i < 2; i++) {
        k_wfuse<<<768, 256, 0, stream>>>(Wih[i], W[i], bW[i], Wfb[i], vib[i]);
        k_wpack<<<192, 256, 0, stream>>>(Wfb[i], Whh[i], Wpk[i]);
    }

    // CSR build (by dst), parallel scan
    k_zeroi<<<(NN + 255) / 256, 256, 0, stream>>>(cnt, NN);
    k_zeroi<<<(NN + 255) / 256, 256, 0, stream>>>(cur, NN);
    k_hist<<<(EE + 255) / 256, 256, 0, stream>>>(dst, cnt);
    k_scanA<<<40, 1024, 0, stream>>>(cnt, rp, bsum);
    k_scanB<<<1, 64, 0, stream>>>(bsum, boff, rp);
    k_scanC<<<157, 256, 0, stream>>>(rp, boff);
    k_fill<<<(EE + 255) / 256, 256, 0, stream>>>(src, dst, rp, cur, cs);
    k_bounds<<<1, 256, 0, stream>>>(gids, gsb, geb);

    const unsigned short* hcur = hbF;
    unsigned short* hnext = hA;
    for (int li = 0; li < 2; li++) {
        for (int s = 0; s < 3; s++) {
            k_aggr<<<10000, 256, 0, stream>>>(hcur, rp, cs, agg);
            int fin = (s == 2) ? 1 : 0;
            k_gru<<<2500, 256, 0, stream>>>(agg, hcur, (const char*)Wpk[li], bih[li], bhh[li],
                                            vib[li], cnt, hnext, fin);
            hcur = hnext;
            hnext = (hnext == hA) ? hB : hA;
        }
    }
    k_gate<<<10000, 256, 0, stream>>>(hcur, Wg, bg, gate);
    k_pool<<<BB, 256, 0, stream>>>(hcur, gate, gsb, geb, pooled);
    k_out<<<BB, 64, 0, stream>>>(pooled, Wo, bo, out);
}